// Round 1
// baseline (127.335 us; speedup 1.0000x reference)
//
#include <hip/hip_runtime.h>

// CLUB loss, algebraically collapsed:
//   out = -0.5/N * P  +  0.5/N^2 * ( <Sx2,Sinv> - 2<Sx,Smuinv> + N*Smu2inv )
// where per-column (d) sums over rows:
//   Sinv[d]  = sum_i exp(-lv[i,d])
//   Smuinv[d]= sum_i mu[i,d]*exp(-lv[i,d])
//   Sx[d]    = sum_j x[j,d]
//   Sx2[d]   = sum_j x[j,d]^2
// and scalars:
//   P       = sum_{i,d} (x[i,d]-mu[i,d])^2 * exp(-lv[i,d])
//   Smu2inv = sum_{i,d} mu[i,d]^2 * exp(-lv[i,d])

#define Bb   8
#define Dd   512
#define HWs  784          // 28*28
#define Nn   6272         // Bb*HWs
#define CC   16           // columns per block
#define RR   112          // rows (hw positions) per block
#define CCH  (Dd / CC)    // 32
#define RCH  (HWs / RR)   // 7
#define PAD  113          // LDS leading-dim pad (odd -> conflict-free)

// ws layout: float[0,512)=Sinv [512,1024)=Smuinv [1024,1536)=Sx [1536,2048)=Sx2
//            then two doubles at byte offset 8192: P, Smu2inv

__global__ __launch_bounds__(256) void club_pass1(
    const float* __restrict__ x, const float* __restrict__ p_mu,
    const float* __restrict__ p_lv, float* __restrict__ ws)
{
    __shared__ float xs[CC * PAD];
    __shared__ float red[256];

    const int t   = threadIdx.x;
    const int bid = blockIdx.x;
    const int bb  = bid / (CCH * RCH);
    const int rem = bid - bb * (CCH * RCH);
    const int cc  = rem / RCH;
    const int rc  = rem - cc * RCH;
    const int c0  = cc * CC;
    const int hw0 = rc * RR;

    // ---- stage x tile (transposed layout) into LDS, coalesced float4 ----
    // x[bb][c0+c][hw0+r]; per c: RR contiguous floats = 28 float4 (16B aligned)
    const float* xbase = x + (size_t)bb * Dd * HWs + (size_t)c0 * HWs + hw0;
    for (int idx = t; idx < CC * (RR / 4); idx += 256) {
        const int c  = idx / (RR / 4);
        const int r4 = idx - c * (RR / 4);
        const float4 v = *(const float4*)(xbase + (size_t)c * HWs + r4 * 4);
        const int la = c * PAD + r4 * 4;
        xs[la + 0] = v.x; xs[la + 1] = v.y; xs[la + 2] = v.z; xs[la + 3] = v.w;
    }
    __syncthreads();

    // ---- main accumulation: thread owns column (c0 + t&15), rows rb+16k ----
    const int cl = t & 15;
    const int rb = t >> 4;
    const int cg = c0 + cl;

    float sInv = 0.f, sMu = 0.f, sX = 0.f, sX2 = 0.f, sP = 0.f, sM2 = 0.f;

    const size_t rowbase = (size_t)(bb * HWs + hw0) * Dd + cg;
    const float* mu_p = p_mu + rowbase;
    const float* lv_p = p_lv + rowbase;

#pragma unroll
    for (int k = 0; k < RR / 16; ++k) {
        const int r = rb + (k << 4);
        const float mu  = mu_p[(size_t)r * Dd];
        const float lv  = lv_p[(size_t)r * Dd];
        const float iev = expf(-lv);
        const float xv  = xs[cl * PAD + r];
        const float dxm = xv - mu;
        sP   += dxm * dxm * iev;
        sInv += iev;
        const float mi = mu * iev;
        sMu  += mi;
        sM2  += mu * mi;
        sX   += xv;
        sX2  += xv * xv;
    }

    // ---- per-column tree reduce (stride 16 keeps column congruence) ----
    auto colreduce = [&](float v, float* dst) {
        red[t] = v; __syncthreads();
        if (t < 128) red[t] += red[t + 128]; __syncthreads();
        if (t <  64) red[t] += red[t +  64]; __syncthreads();
        if (t <  32) red[t] += red[t +  32]; __syncthreads();
        if (t <  16) atomicAdd(dst + c0 + t, red[t] + red[t + 16]);
        __syncthreads();
    };
    colreduce(sInv, ws + 0);
    colreduce(sMu,  ws + 512);
    colreduce(sX,   ws + 1024);
    colreduce(sX2,  ws + 1536);

    // ---- scalar reduces -> fp64 atomics (P and Smu2inv need the precision) ----
    auto scalreduce = [&](float v, double* dst) {
        red[t] = v; __syncthreads();
        for (int s = 128; s > 0; s >>= 1) {
            if (t < s) red[t] += red[t + s];
            __syncthreads();
        }
        if (t == 0) atomicAdd(dst, (double)red[0]);
        __syncthreads();
    };
    double* wsd = (double*)((char*)ws + 8192);
    scalreduce(sP,  wsd + 0);
    scalreduce(sM2, wsd + 1);
}

__global__ __launch_bounds__(256) void club_pass2(
    const float* __restrict__ ws, float* __restrict__ out)
{
    __shared__ double red[256];
    const int t = threadIdx.x;
    double acc = 0.0;
    for (int d0 = t; d0 < Dd; d0 += 256) {
        const double sinv = ws[d0];
        const double smu  = ws[512 + d0];
        const double sx   = ws[1024 + d0];
        const double sx2  = ws[1536 + d0];
        acc += sx2 * sinv - 2.0 * sx * smu;
    }
    red[t] = acc; __syncthreads();
    for (int s = 128; s > 0; s >>= 1) {
        if (t < s) red[t] += red[t + s];
        __syncthreads();
    }
    if (t == 0) {
        const double* wsd = (const double*)((const char*)ws + 8192);
        const double P   = wsd[0];
        const double M2  = wsd[1];
        const double sumD = red[0] + (double)Nn * M2;
        const double res  = (-0.5 / (double)Nn) * P
                          + (0.5 / ((double)Nn * (double)Nn)) * sumD;
        out[0] = (float)res;
    }
}

extern "C" void kernel_launch(void* const* d_in, const int* in_sizes, int n_in,
                              void* d_out, int out_size, void* d_ws, size_t ws_size,
                              hipStream_t stream) {
    const float* x    = (const float*)d_in[0];
    const float* p_mu = (const float*)d_in[1];
    const float* p_lv = (const float*)d_in[2];
    float* ws = (float*)d_ws;

    // zero accumulators (ws is re-poisoned to 0xAA before every timed call)
    hipMemsetAsync(d_ws, 0, 8192 + 2 * sizeof(double), stream);

    club_pass1<<<Bb * CCH * RCH, 256, 0, stream>>>(x, p_mu, p_lv, ws);
    club_pass2<<<1, 256, 0, stream>>>(ws, (float*)d_out);
}